// Round 2
// baseline (1301.966 us; speedup 1.0000x reference)
//
#include <hip/hip_runtime.h>
#include <cstdint>

typedef __bf16 bf16;
typedef __bf16 bf16x4 __attribute__((ext_vector_type(4)));
typedef __bf16 bf16x8 __attribute__((ext_vector_type(8)));
typedef float  f32x4  __attribute__((ext_vector_type(4)));

#define LOG2E 1.44269504088896340736f

__device__ __forceinline__ f32x4 mfma16(bf16x8 a, bf16x8 b, f32x4 c) {
  return __builtin_amdgcn_mfma_f32_16x16x32_bf16(a, b, c, 0, 0, 0);
}

__device__ __forceinline__ bf16x8 loadcvt8(const float* p) {
  const f32x4* q = (const f32x4*)p;
  f32x4 a = q[0], b = q[1];
  bf16x8 r;
  r[0] = (bf16)a[0]; r[1] = (bf16)a[1]; r[2] = (bf16)a[2]; r[3] = (bf16)a[3];
  r[4] = (bf16)b[0]; r[5] = (bf16)b[1]; r[6] = (bf16)b[2]; r[7] = (bf16)b[3];
  return r;
}

// ---------------- convert f32 -> bf16 for X0 and all weights (one kernel) ----------------
// unit = float4. boundaries: X0 786432 | fc1w 147456 | fc2w 147456 | ipw 442368 | outw 147456
__global__ __launch_bounds__(256) void cvt_all(
    const float* __restrict__ x0, const float* __restrict__ w1,
    const float* __restrict__ w2, const float* __restrict__ wip,
    const float* __restrict__ wo,
    bf16* __restrict__ dx0, bf16* __restrict__ dw1, bf16* __restrict__ dw2,
    bf16* __restrict__ dwip, bf16* __restrict__ dwo)
{
  int i = blockIdx.x * 256 + threadIdx.x;
  const float* s; bf16* d; int base;
  if      (i <  786432) { s = x0;  d = dx0;  base = 0; }
  else if (i <  933888) { s = w1;  d = dw1;  base = 786432; }
  else if (i < 1081344) { s = w2;  d = dw2;  base = 933888; }
  else if (i < 1523712) { s = wip; d = dwip; base = 1081344; }
  else                  { s = wo;  d = dwo;  base = 1523712; }
  int j = i - base;
  f32x4 v = ((const f32x4*)s)[j];
  bf16x4 r;
  r[0] = (bf16)v[0]; r[1] = (bf16)v[1]; r[2] = (bf16)v[2]; r[3] = (bf16)v[3];
  ((bf16x4*)d)[j] = r;
}

// ---------------- generic GEMM: out = act(A[M,768] @ W[N,768]^T + bias) ----------------
// grid (M/64, N/64), block 256. wave w: rows base+16w x 64 cols.
template<int RELU, int OUTF32>
__global__ __launch_bounds__(256) void gemm_bt(
    const bf16* __restrict__ A, const bf16* __restrict__ W,
    const float* __restrict__ bias, bf16* __restrict__ outb,
    float* __restrict__ outf, int N)
{
  const int w = threadIdx.x >> 6, lane = threadIdx.x & 63;
  const int q = lane >> 4, c = lane & 15;
  const int rbase = blockIdx.x * 64 + w * 16;
  const int nb = blockIdx.y * 64;
  f32x4 acc[4] = {};
  const bf16* Ar = A + (size_t)(rbase + c) * 768 + q * 8;
  const bf16* W0 = W + (size_t)(nb + c) * 768 + q * 8;
  for (int ks = 0; ks < 24; ++ks) {
    bf16x8 a = *(const bf16x8*)(Ar + ks * 32);
#pragma unroll
    for (int nt = 0; nt < 4; ++nt) {
      bf16x8 b = *(const bf16x8*)(W0 + (size_t)nt * 16 * 768 + ks * 32);
      acc[nt] = mfma16(a, b, acc[nt]);
    }
  }
#pragma unroll
  for (int nt = 0; nt < 4; ++nt) {
#pragma unroll
    for (int j = 0; j < 4; ++j) {
      int row = rbase + q * 4 + j;
      int col = nb + nt * 16 + c;
      float v = acc[nt][j] + bias[col];
      if (RELU) v = fmaxf(v, 0.f);
      if (OUTF32) outf[(size_t)row * N + col] = v;
      else        outb[(size_t)row * N + col] = (bf16)v;
    }
  }
}

// ---------------- 64x64 tile transpose: dst[col][row] = src[row][colOff+col] ----------------
// grid (64, 12) for 4096 rows x 768 cols. dst is [768][4096].
__global__ __launch_bounds__(256) void transpose_bf16(
    const bf16* __restrict__ src, bf16* __restrict__ dst, int stride, int colOff)
{
  __shared__ bf16 t[64][72];
  const int br = blockIdx.x, bc = blockIdx.y;
  {
    int ir = threadIdx.x >> 2, icb = (threadIdx.x & 3) * 16;
    const bf16* srow = src + (size_t)(br * 64 + ir) * stride + colOff + bc * 64 + icb;
    *(bf16x8*)&t[ir][icb] = *(const bf16x8*)srow;
    *(bf16x8*)&t[ir][icb + 8] = *(const bf16x8*)(srow + 8);
  }
  __syncthreads();
  {
    int oc = threadIdx.x >> 2, orb = (threadIdx.x & 3) * 16;
    bf16x8 v0, v1;
#pragma unroll
    for (int j = 0; j < 8; ++j) { v0[j] = t[orb + j][oc]; v1[j] = t[orb + 8 + j][oc]; }
    bf16* drow = dst + (size_t)(bc * 64 + oc) * 4096 + br * 64 + orb;
    *(bf16x8*)drow = v0;
    *(bf16x8*)(drow + 8) = v1;
  }
}

// ---------------- flash attention: 12 heads, hd=64, N=4096 ----------------
// grid 768 = h*64 + qtile; block 256 (4 waves, 16 q-rows each)
__global__ __launch_bounds__(256) void attn_kernel(
    const bf16* __restrict__ qkv, const bf16* __restrict__ vt, bf16* __restrict__ o)
{
  const int h = blockIdx.x >> 6;
  const int qt = blockIdx.x & 63;
  const int w = threadIdx.x >> 6, lane = threadIdx.x & 63;
  const int q2 = lane >> 4, c = lane & 15;
  const int qbase = qt * 64 + w * 16;
  __shared__ bf16 Pl[4][16][72];
  const bf16* Qr = qkv + (size_t)(qbase + c) * 2304 + h * 64 + q2 * 8;
  bf16x8 a0 = *(const bf16x8*)(Qr);
  bf16x8 a1 = *(const bf16x8*)(Qr + 32);
  const bf16* Kbase = qkv + 768 + h * 64 + q2 * 8;
  const bf16* Vbase = vt + (size_t)(h * 64 + c) * 4096 + q2 * 8;
  f32x4 oa[4] = {};
  float mi[4] = {-3e38f, -3e38f, -3e38f, -3e38f};
  float li[4] = {0.f, 0.f, 0.f, 0.f};
  for (int jt = 0; jt < 64; ++jt) {
    const int kvb = jt * 64;
    f32x4 s[4];
#pragma unroll
    for (int nt = 0; nt < 4; ++nt) {
      const bf16* Kr = Kbase + (size_t)(kvb + nt * 16 + c) * 2304;
      f32x4 t = {};
      t = mfma16(a0, *(const bf16x8*)(Kr), t);
      t = mfma16(a1, *(const bf16x8*)(Kr + 32), t);
      s[nt] = t;
    }
    float alpha[4];
#pragma unroll
    for (int j = 0; j < 4; ++j) {
      float mx = -3e38f;
#pragma unroll
      for (int nt = 0; nt < 4; ++nt) { s[nt][j] *= 0.125f; mx = fmaxf(mx, s[nt][j]); }
#pragma unroll
      for (int off = 8; off; off >>= 1) mx = fmaxf(mx, __shfl_xor(mx, off, 16));
      float mn = fmaxf(mi[j], mx);
      alpha[j] = exp2f((mi[j] - mn) * LOG2E);
      float r = 0.f;
#pragma unroll
      for (int nt = 0; nt < 4; ++nt) { float p = exp2f((s[nt][j] - mn) * LOG2E); s[nt][j] = p; r += p; }
#pragma unroll
      for (int off = 8; off; off >>= 1) r += __shfl_xor(r, off, 16);
      li[j] = li[j] * alpha[j] + r;
      mi[j] = mn;
    }
#pragma unroll
    for (int nt = 0; nt < 4; ++nt)
#pragma unroll
      for (int j = 0; j < 4; ++j)
        Pl[w][q2 * 4 + j][nt * 16 + c] = (bf16)s[nt][j];
#pragma unroll
    for (int dt = 0; dt < 4; ++dt)
#pragma unroll
      for (int j = 0; j < 4; ++j) oa[dt][j] *= alpha[j];
    __syncthreads();
    bf16x8 p0 = *(const bf16x8*)(&Pl[w][c][q2 * 8]);
    bf16x8 p1 = *(const bf16x8*)(&Pl[w][c][32 + q2 * 8]);
#pragma unroll
    for (int dt = 0; dt < 4; ++dt) {
      const bf16* Vr = Vbase + (size_t)dt * 16 * 4096 + kvb;
      oa[dt] = mfma16(p0, *(const bf16x8*)(Vr), oa[dt]);
      oa[dt] = mfma16(p1, *(const bf16x8*)(Vr + 32), oa[dt]);
    }
    __syncthreads();
  }
#pragma unroll
  for (int dt = 0; dt < 4; ++dt)
#pragma unroll
    for (int j = 0; j < 4; ++j) {
      int row = qbase + q2 * 4 + j;
      int col = h * 64 + dt * 16 + c;
      o[(size_t)row * 768 + col] = (bf16)(oa[dt][j] / li[j]);
    }
}

// ---------------- residual + layernorm: X = LN(0.5*x0 + 0.5*y)*g + b ----------------
// block 256 = 4 waves, 1 row per wave; grid 1024.
__global__ __launch_bounds__(256) void ln_kernel(
    const float* __restrict__ x0, const float* __restrict__ y,
    const float* __restrict__ g, const float* __restrict__ b,
    float* __restrict__ X, bf16* __restrict__ Xb, float* __restrict__ xn2)
{
  const int w = threadIdx.x >> 6, lane = threadIdx.x & 63;
  const int row = blockIdx.x * 4 + w;
  const float* xr = x0 + (size_t)row * 768;
  const float* yr = y + (size_t)row * 768;
  float z[12]; float s = 0.f;
#pragma unroll
  for (int i = 0; i < 12; ++i) {
    int col = lane + i * 64;
    float zz = 0.5f * xr[col] + 0.5f * yr[col];
    z[i] = zz; s += zz;
  }
#pragma unroll
  for (int off = 32; off; off >>= 1) s += __shfl_xor(s, off, 64);
  float mu = s * (1.f / 768.f);
  float v = 0.f;
#pragma unroll
  for (int i = 0; i < 12; ++i) { float d = z[i] - mu; v += d * d; }
#pragma unroll
  for (int off = 32; off; off >>= 1) v += __shfl_xor(v, off, 64);
  float rstd = rsqrtf(v * (1.f / 768.f) + 1e-5f);
  float sn = 0.f;
#pragma unroll
  for (int i = 0; i < 12; ++i) {
    int col = lane + i * 64;
    float xv = (z[i] - mu) * rstd * g[col] + b[col];
    X[(size_t)row * 768 + col] = xv;
    Xb[(size_t)row * 768 + col] = (bf16)xv;
    sn += xv * xv;
  }
#pragma unroll
  for (int off = 32; off; off >>= 1) sn += __shfl_xor(sn, off, 64);
  if (lane == 0) xn2[row] = sn;
}

// ---------------- gather C0 = X[idx], cn0 = rownorm2(C0), zero control ----------------
__global__ __launch_bounds__(256) void gather_init(
    const float* __restrict__ X, const int* __restrict__ idx,
    float* __restrict__ Cbuf, float* __restrict__ cn,
    float* __restrict__ asum, float* __restrict__ diff,
    int* flag, int* rp, int* dctr)
{
  const int k = blockIdx.x;
  const int src = idx[k];
  __shared__ float red[4];
  float s = 0.f;
#pragma unroll
  for (int u = 0; u < 3; ++u) {
    int d = u * 256 + threadIdx.x;
    float v = X[(size_t)src * 768 + d];
    Cbuf[(size_t)k * 768 + d] = v;
    s += v * v;
  }
#pragma unroll
  for (int off = 32; off; off >>= 1) s += __shfl_xor(s, off, 64);
  if ((threadIdx.x & 63) == 0) red[threadIdx.x >> 6] = s;
  __syncthreads();
  if (threadIdx.x == 0) cn[k] = red[0] + red[1] + red[2] + red[3];
  if (k == 0) {
    if (threadIdx.x < 64) {
      asum[threadIdx.x] = 0.f;
      asum[64 + threadIdx.x] = 0.f;
      cn[64 + threadIdx.x] = 0.f;
    }
    if (threadIdx.x == 0) {
      diff[0] = 0.f; diff[1] = 0.f; *flag = 0; *rp = 0; *dctr = 0;
    }
  }
}

// ---------------- DKM step part 1: G = X@C^T, a = softmax(-2*d), a_sum ----------------
// grid 256 (16 X-rows each), block 256.
__global__ __launch_bounds__(256) void dkm_assign(
    const float* __restrict__ Call, const float* __restrict__ cnall, int t,
    const bf16* __restrict__ Xb, const float* __restrict__ xn2,
    float* __restrict__ a_out, bf16* __restrict__ aT,
    float* __restrict__ asumall, const int* flag)
{
  if (*(volatile const int*)flag) return;
  const float* C  = Call + (size_t)(t & 1) * 49152;
  const float* cn = cnall + (t & 1) * 64;
  float* asum = asumall + (t & 1) * 64;
  __shared__ float Gs[16][64];
  __shared__ float asl[64];
  const int w = threadIdx.x >> 6, lane = threadIdx.x & 63;
  const int q2 = lane >> 4, c = lane & 15;
  const int rbase = blockIdx.x * 16;
  f32x4 acc = {};
  const bf16* Ar = Xb + (size_t)(rbase + c) * 768 + q2 * 8;
  const float* Cr = C + (size_t)(w * 16 + c) * 768 + q2 * 8;
  for (int ks = 0; ks < 24; ++ks) {
    bf16x8 a = *(const bf16x8*)(Ar + ks * 32);
    bf16x8 b = loadcvt8(Cr + ks * 32);
    acc = mfma16(a, b, acc);
  }
  if (threadIdx.x < 64) asl[threadIdx.x] = 0.f;
#pragma unroll
  for (int j = 0; j < 4; ++j) Gs[q2 * 4 + j][w * 16 + c] = acc[j];
  __syncthreads();
  const int row = threadIdx.x >> 4, ci = threadIdx.x & 15;
  const float xn = xn2[rbase + row];
  float lg[4];
#pragma unroll
  for (int u = 0; u < 4; ++u) {
    int col = ci + u * 16;
    float d2 = xn + cn[col] - 2.f * Gs[row][col];
    lg[u] = -2.f * sqrtf(fmaxf(d2, 0.f));   // -d / TEMP, TEMP=0.5
  }
  float mx = fmaxf(fmaxf(lg[0], lg[1]), fmaxf(lg[2], lg[3]));
#pragma unroll
  for (int off = 8; off; off >>= 1) mx = fmaxf(mx, __shfl_xor(mx, off, 16));
  float sum = 0.f;
#pragma unroll
  for (int u = 0; u < 4; ++u) { float e = exp2f((lg[u] - mx) * LOG2E); lg[u] = e; sum += e; }
#pragma unroll
  for (int off = 8; off; off >>= 1) sum += __shfl_xor(sum, off, 16);
#pragma unroll
  for (int u = 0; u < 4; ++u) {
    int col = ci + u * 16;
    float av = lg[u] / sum;
    a_out[(size_t)(rbase + row) * 64 + col] = av;
    aT[(size_t)col * 4096 + rbase + row] = (bf16)av;
    atomicAdd(&asl[col], av);
  }
  __syncthreads();
  if (threadIdx.x < 64) atomicAdd(&asum[threadIdx.x], asl[threadIdx.x]);
}

// ---------------- DKM step part 2: C_new = a^T @ X / a_sum, diff, flag ----------------
// grid 192 (4x48 tiles of 16x16), block 256 (4 waves split K).
__global__ __launch_bounds__(256) void dkm_update(
    float* __restrict__ Call, float* __restrict__ cnall, int t,
    const bf16* __restrict__ aT, const bf16* __restrict__ Xt,
    float* __restrict__ asumall, float* __restrict__ diffall,
    int* flag, int* rp, int* dctr)
{
  if (*(volatile int*)flag) return;
  const int w = threadIdx.x >> 6, lane = threadIdx.x & 63;
  const int q2 = lane >> 4, c = lane & 15;
  const int tr = blockIdx.x / 48, tc = blockIdx.x % 48;
  f32x4 acc = {};
  const bf16* Ar = aT + (size_t)(tr * 16 + c) * 4096 + q2 * 8;
  const bf16* Br = Xt + (size_t)(tc * 16 + c) * 4096 + q2 * 8;
  for (int i = 0; i < 32; ++i) {
    int kb = (w + i * 4) * 32;
    acc = mfma16(*(const bf16x8*)(Ar + kb), *(const bf16x8*)(Br + kb), acc);
  }
  __shared__ float red[4][16][16];
  __shared__ float cnl[16];
  __shared__ float dred[4];
#pragma unroll
  for (int j = 0; j < 4; ++j) red[w][q2 * 4 + j][c] = acc[j];
  if (threadIdx.x < 16) cnl[threadIdx.x] = 0.f;
  __syncthreads();
  const int r = threadIdx.x >> 4, cl = threadIdx.x & 15;
  float s = red[0][r][cl] + red[1][r][cl] + red[2][r][cl] + red[3][r][cl];
  const int cluster = tr * 16 + r, dcol = tc * 16 + cl;
  float denom = asumall[(t & 1) * 64 + cluster] + 1e-6f;
  float cnew = s / denom;
  size_t cidx = (size_t)cluster * 768 + dcol;
  float cold = Call[(size_t)(t & 1) * 49152 + cidx];
  Call[(size_t)((t + 1) & 1) * 49152 + cidx] = cnew;
  atomicAdd(&cnl[r], cnew * cnew);
  float dv = fabsf(cnew - cold);
#pragma unroll
  for (int off = 32; off; off >>= 1) dv += __shfl_xor(dv, off, 64);
  if (lane == 0) dred[w] = dv;
  __syncthreads();
  if (threadIdx.x < 16)
    atomicAdd(&cnall[((t + 1) & 1) * 64 + tr * 16 + threadIdx.x], cnl[threadIdx.x]);
  if (threadIdx.x == 0) {
    atomicAdd(&diffall[t & 1], dred[0] + dred[1] + dred[2] + dred[3]);
    __threadfence();
    int old = atomicAdd(dctr, 1);
    if (old == 191) {   // last block of this dispatch
      float dtot = atomicAdd(&diffall[t & 1], 0.f);
      if (dtot <= 1e-4f) { *flag = 1; *rp = (t & 1); }
      diffall[(t + 1) & 1] = 0.f;
      for (int i = 0; i < 64; ++i) {
        asumall[((t + 1) & 1) * 64 + i] = 0.f;
        cnall[(t & 1) * 64 + i] = 0.f;
      }
      *dctr = 0;
    }
  }
}

// ---------------- final: copy converged C (parity rp) to d_out ----------------
__global__ __launch_bounds__(256) void copy_c(const float* __restrict__ Call,
                                              const int* __restrict__ rp,
                                              float* __restrict__ out)
{
  const float* src = Call + (size_t)(*rp) * 49152;
  int i = blockIdx.x * 256 + threadIdx.x;
#pragma unroll
  for (int u = 0; u < 4; ++u) out[i + u * 12288] = src[i + u * 12288];
}

extern "C" void kernel_launch(void* const* d_in, const int* in_sizes, int n_in,
                              void* d_out, int out_size, void* d_ws, size_t ws_size,
                              hipStream_t stream) {
  const float* x0   = (const float*)d_in[0];
  const float* fc1w = (const float*)d_in[1];
  const float* fc1b = (const float*)d_in[2];
  const float* fc2w = (const float*)d_in[3];
  const float* fc2b = (const float*)d_in[4];
  const float* ipw  = (const float*)d_in[5];
  const float* ipb  = (const float*)d_in[6];
  const float* outw = (const float*)d_in[7];
  const float* outbias = (const float*)d_in[8];
  const float* lng  = (const float*)d_in[9];
  const float* lnb  = (const float*)d_in[10];
  const int*   idx  = (const int*)d_in[11];

  char* p = (char*)d_ws;
  auto take = [&](size_t n) { char* r = p; p += (n + 255) & ~(size_t)255; return r; };
  bf16* X0B   = (bf16*)take((size_t)4096 * 768 * 2);
  bf16* W1B   = (bf16*)take((size_t)768 * 768 * 2);
  bf16* FC2WB = (bf16*)take((size_t)768 * 768 * 2);
  bf16* IPWB  = (bf16*)take((size_t)2304 * 768 * 2);
  bf16* OUTWB = (bf16*)take((size_t)768 * 768 * 2);
  bf16* HB    = (bf16*)take((size_t)4096 * 768 * 2);
  bf16* QKVB  = (bf16*)take((size_t)4096 * 2304 * 2);
  bf16* VT    = (bf16*)take((size_t)768 * 4096 * 2);
  bf16* OB    = (bf16*)take((size_t)4096 * 768 * 2);
  bf16* O2B   = (bf16*)take((size_t)4096 * 768 * 2);
  float* YF   = (float*)take((size_t)4096 * 768 * 4);
  float* XF   = (float*)take((size_t)4096 * 768 * 4);
  bf16* XBB   = (bf16*)take((size_t)4096 * 768 * 2);
  bf16* XTB   = (bf16*)take((size_t)768 * 4096 * 2);
  float* XN2  = (float*)take((size_t)4096 * 4);
  float* CB   = (float*)take((size_t)2 * 49152 * 4);
  bf16* ATB   = (bf16*)take((size_t)64 * 4096 * 2);
  float* ASUM = (float*)take(2 * 64 * 4);
  float* CN   = (float*)take(2 * 64 * 4);
  float* CTRL = (float*)take(256);
  float* DIFF = CTRL;               // [2] floats
  int* FLAG = (int*)(CTRL + 2);
  int* RP   = (int*)(CTRL + 3);
  int* DCTR = (int*)(CTRL + 4);

  float* aout = (float*)d_out + 49152;

  cvt_all<<<6528, 256, 0, stream>>>(x0, fc1w, fc2w, ipw, outw, X0B, W1B, FC2WB, IPWB, OUTWB);
  gemm_bt<1, 0><<<dim3(64, 12), 256, 0, stream>>>(X0B, W1B, fc1b, HB, nullptr, 768);
  gemm_bt<0, 0><<<dim3(64, 36), 256, 0, stream>>>(HB, IPWB, ipb, QKVB, nullptr, 2304);
  transpose_bf16<<<dim3(64, 12), 256, 0, stream>>>(QKVB, VT, 2304, 1536);
  attn_kernel<<<768, 256, 0, stream>>>(QKVB, VT, OB);
  gemm_bt<0, 0><<<dim3(64, 12), 256, 0, stream>>>(OB, OUTWB, outbias, O2B, nullptr, 768);
  gemm_bt<1, 1><<<dim3(64, 12), 256, 0, stream>>>(O2B, FC2WB, fc2b, nullptr, YF, 768);
  ln_kernel<<<1024, 256, 0, stream>>>(x0, YF, lng, lnb, XF, XBB, XN2);
  transpose_bf16<<<dim3(64, 12), 256, 0, stream>>>(XBB, XTB, 768, 0);
  gather_init<<<64, 256, 0, stream>>>(XF, idx, CB, CN, ASUM, DIFF, FLAG, RP, DCTR);
  for (int t = 0; t <= 100; ++t) {
    dkm_assign<<<256, 256, 0, stream>>>(CB, CN, t, XBB, XN2, aout, ATB, ASUM, FLAG);
    dkm_update<<<192, 256, 0, stream>>>(CB, CN, t, ATB, XTB, ASUM, DIFF, FLAG, RP, DCTR);
  }
  copy_c<<<48, 256, 0, stream>>>(CB, RP, (float*)d_out);
}

// Round 3
// 1012.636 us; speedup vs baseline: 1.2857x; 1.2857x over previous
//
#include <hip/hip_runtime.h>
#include <cstdint>

typedef __bf16 bf16;
typedef __bf16 bf16x4 __attribute__((ext_vector_type(4)));
typedef __bf16 bf16x8 __attribute__((ext_vector_type(8)));
typedef float  f32x4  __attribute__((ext_vector_type(4)));

#define LOG2E 1.44269504088896340736f

__device__ __forceinline__ f32x4 mfma16(bf16x8 a, bf16x8 b, f32x4 c) {
  return __builtin_amdgcn_mfma_f32_16x16x32_bf16(a, b, c, 0, 0, 0);
}

// async global->LDS, 16B per lane; LDS dest must be wave-uniform base + lane*16
__device__ __forceinline__ void gl2lds16(const bf16* g, bf16* l) {
  __builtin_amdgcn_global_load_lds(
      (const __attribute__((address_space(1))) unsigned int*)g,
      (__attribute__((address_space(3))) unsigned int*)l, 16, 0, 0);
}

// ---------------- convert f32 -> bf16 for X0 and all weights (one kernel) ----------------
__global__ __launch_bounds__(256) void cvt_all(
    const float* __restrict__ x0, const float* __restrict__ w1,
    const float* __restrict__ w2, const float* __restrict__ wip,
    const float* __restrict__ wo,
    bf16* __restrict__ dx0, bf16* __restrict__ dw1, bf16* __restrict__ dw2,
    bf16* __restrict__ dwip, bf16* __restrict__ dwo)
{
  int i = blockIdx.x * 256 + threadIdx.x;
  const float* s; bf16* d; int base;
  if      (i <  786432) { s = x0;  d = dx0;  base = 0; }
  else if (i <  933888) { s = w1;  d = dw1;  base = 786432; }
  else if (i < 1081344) { s = w2;  d = dw2;  base = 933888; }
  else if (i < 1523712) { s = wip; d = dwip; base = 1081344; }
  else                  { s = wo;  d = dwo;  base = 1523712; }
  int j = i - base;
  f32x4 v = ((const f32x4*)s)[j];
  bf16x4 r;
  r[0] = (bf16)v[0]; r[1] = (bf16)v[1]; r[2] = (bf16)v[2]; r[3] = (bf16)v[3];
  ((bf16x4*)d)[j] = r;
}

// ---------------- generic GEMM: out = act(A[M,768] @ W[N,768]^T + bias) ----------------
template<int RELU, int OUTF32>
__global__ __launch_bounds__(256) void gemm_bt(
    const bf16* __restrict__ A, const bf16* __restrict__ W,
    const float* __restrict__ bias, bf16* __restrict__ outb,
    float* __restrict__ outf, int N)
{
  const int w = threadIdx.x >> 6, lane = threadIdx.x & 63;
  const int q = lane >> 4, c = lane & 15;
  const int rbase = blockIdx.x * 64 + w * 16;
  const int nb = blockIdx.y * 64;
  f32x4 acc[4] = {};
  const bf16* Ar = A + (size_t)(rbase + c) * 768 + q * 8;
  const bf16* W0 = W + (size_t)(nb + c) * 768 + q * 8;
  for (int ks = 0; ks < 24; ++ks) {
    bf16x8 a = *(const bf16x8*)(Ar + ks * 32);
#pragma unroll
    for (int nt = 0; nt < 4; ++nt) {
      bf16x8 b = *(const bf16x8*)(W0 + (size_t)nt * 16 * 768 + ks * 32);
      acc[nt] = mfma16(a, b, acc[nt]);
    }
  }
#pragma unroll
  for (int nt = 0; nt < 4; ++nt) {
#pragma unroll
    for (int j = 0; j < 4; ++j) {
      int row = rbase + q * 4 + j;
      int col = nb + nt * 16 + c;
      float v = acc[nt][j] + bias[col];
      if (RELU) v = fmaxf(v, 0.f);
      if (OUTF32) outf[(size_t)row * N + col] = v;
      else        outb[(size_t)row * N + col] = (bf16)v;
    }
  }
}

// ---------------- 64x64 tile transpose ----------------
__global__ __launch_bounds__(256) void transpose_bf16(
    const bf16* __restrict__ src, bf16* __restrict__ dst, int stride, int colOff)
{
  __shared__ bf16 t[64][72];
  const int br = blockIdx.x, bc = blockIdx.y;
  {
    int ir = threadIdx.x >> 2, icb = (threadIdx.x & 3) * 16;
    const bf16* srow = src + (size_t)(br * 64 + ir) * stride + colOff + bc * 64 + icb;
    *(bf16x8*)&t[ir][icb] = *(const bf16x8*)srow;
    *(bf16x8*)&t[ir][icb + 8] = *(const bf16x8*)(srow + 8);
  }
  __syncthreads();
  {
    int oc = threadIdx.x >> 2, orb = (threadIdx.x & 3) * 16;
    bf16x8 v0, v1;
#pragma unroll
    for (int j = 0; j < 8; ++j) { v0[j] = t[orb + j][oc]; v1[j] = t[orb + 8 + j][oc]; }
    bf16* drow = dst + (size_t)(bc * 64 + oc) * 4096 + br * 64 + orb;
    *(bf16x8*)drow = v0;
    *(bf16x8*)(drow + 8) = v1;
  }
}

// ---------------- flash attention v2: LDS-staged KV (dbuf), no-max softmax ----------------
// grid 768 = h*64 + qtile; block 256 (4 waves, 16 q-rows each)
// Ks/Vs XOR-swizzled: element-group g' = g ^ (row&7); applied on the GLOBAL side of
// global_load_lds (LDS dest must stay base+lane*16); b128 reads then hit all 32 banks.
__global__ __launch_bounds__(256) void attn_kernel(
    const bf16* __restrict__ qkv, const bf16* __restrict__ vt, bf16* __restrict__ o)
{
  const int h = blockIdx.x >> 6;
  const int qt = blockIdx.x & 63;
  const int w = threadIdx.x >> 6, lane = threadIdx.x & 63;
  const int q2 = lane >> 4, c = lane & 15;
  const int qbase = qt * 64 + w * 16;
  __shared__ bf16 Ks[2][64][64];
  __shared__ bf16 Vs[2][64][64];
  __shared__ bf16 Pl[4][16][72];

  const bf16* Qr = qkv + (size_t)(qbase + c) * 2304 + h * 64 + q2 * 8;
  bf16x8 a0 = *(const bf16x8*)(Qr);
  bf16x8 a1 = *(const bf16x8*)(Qr + 32);

  // staging geometry (per wave: rows w*16..w*16+15, 8 rows per call)
  const int srow = lane >> 3;                       // 0..7
  const int sg = ((lane & 7) ^ srow) * 8;           // swizzled source col group
  const bf16* kg = qkv + (size_t)(w * 16 + srow) * 2304 + 768 + h * 64 + sg;
  const bf16* vg = vt + (size_t)(h * 64 + w * 16 + srow) * 4096 + sg;

  auto stage = [&](int jt, int buf) {
    const int kvb = jt * 64;
    gl2lds16(kg + (size_t)kvb * 2304,              &Ks[buf][w * 16][0]);
    gl2lds16(kg + (size_t)(kvb + 8) * 2304,        &Ks[buf][w * 16 + 8][0]);
    gl2lds16(vg + kvb,                             &Vs[buf][w * 16][0]);
    gl2lds16(vg + kvb + 8 * 4096,                  &Vs[buf][w * 16 + 8][0]);
  };

  bf16x8 ones;
#pragma unroll
  for (int i = 0; i < 8; ++i) ones[i] = (bf16)1.0f;

  f32x4 oa[4] = {};
  f32x4 accl = {};
  const int gsw = (q2 ^ (c & 7)) * 8;               // swizzled read group offset
  const float SC = 0.125f * LOG2E;

  stage(0, 0);
  for (int jt = 0; jt < 64; ++jt) {
    const int buf = jt & 1;
    __syncthreads();                 // drains stage(jt); prev-buf reads all done
    if (jt < 63) stage(jt + 1, buf ^ 1);
    // ---- S = Q K^T (scores for 16 q-rows x 64 kv) ----
    f32x4 s[4];
#pragma unroll
    for (int nt = 0; nt < 4; ++nt) {
      const int row = nt * 16 + c;
      bf16x8 b0 = *(const bf16x8*)&Ks[buf][row][gsw];
      bf16x8 b1 = *(const bf16x8*)&Ks[buf][row][gsw ^ 32];
      f32x4 t = {};
      t = mfma16(a0, b0, t);
      t = mfma16(a1, b1, t);
      s[nt] = t;
    }
    // ---- P = exp(S/8) (no max subtraction: |S/8| << 1) ----
#pragma unroll
    for (int nt = 0; nt < 4; ++nt)
#pragma unroll
      for (int j = 0; j < 4; ++j)
        Pl[w][q2 * 4 + j][nt * 16 + c] = (bf16)exp2f(s[nt][j] * SC);
    // ---- P back as A-frags (wave-private LDS, no barrier needed) ----
    bf16x8 p0 = *(const bf16x8*)(&Pl[w][c][q2 * 8]);
    bf16x8 p1 = *(const bf16x8*)(&Pl[w][c][32 + q2 * 8]);
    // row sums via ones-MFMA (replaces shuffle reduction)
    accl = mfma16(p0, ones, accl);
    accl = mfma16(p1, ones, accl);
    // ---- O += P V ----
#pragma unroll
    for (int dt = 0; dt < 4; ++dt) {
      const int row = dt * 16 + c;
      bf16x8 v0 = *(const bf16x8*)&Vs[buf][row][gsw];
      bf16x8 v1 = *(const bf16x8*)&Vs[buf][row][gsw ^ 32];
      oa[dt] = mfma16(p0, v0, oa[dt]);
      oa[dt] = mfma16(p1, v1, oa[dt]);
    }
  }
#pragma unroll
  for (int dt = 0; dt < 4; ++dt)
#pragma unroll
    for (int j = 0; j < 4; ++j) {
      int row = qbase + q2 * 4 + j;
      int col = h * 64 + dt * 16 + c;
      o[(size_t)row * 768 + col] = (bf16)(oa[dt][j] / accl[j]);
    }
}

// ---------------- residual + layernorm ----------------
__global__ __launch_bounds__(256) void ln_kernel(
    const float* __restrict__ x0, const float* __restrict__ y,
    const float* __restrict__ g, const float* __restrict__ b,
    float* __restrict__ X, bf16* __restrict__ Xb, float* __restrict__ xn2)
{
  const int w = threadIdx.x >> 6, lane = threadIdx.x & 63;
  const int row = blockIdx.x * 4 + w;
  const float* xr = x0 + (size_t)row * 768;
  const float* yr = y + (size_t)row * 768;
  float z[12]; float s = 0.f;
#pragma unroll
  for (int i = 0; i < 12; ++i) {
    int col = lane + i * 64;
    float zz = 0.5f * xr[col] + 0.5f * yr[col];
    z[i] = zz; s += zz;
  }
#pragma unroll
  for (int off = 32; off; off >>= 1) s += __shfl_xor(s, off, 64);
  float mu = s * (1.f / 768.f);
  float v = 0.f;
#pragma unroll
  for (int i = 0; i < 12; ++i) { float d = z[i] - mu; v += d * d; }
#pragma unroll
  for (int off = 32; off; off >>= 1) v += __shfl_xor(v, off, 64);
  float rstd = rsqrtf(v * (1.f / 768.f) + 1e-5f);
  float sn = 0.f;
#pragma unroll
  for (int i = 0; i < 12; ++i) {
    int col = lane + i * 64;
    float xv = (z[i] - mu) * rstd * g[col] + b[col];
    X[(size_t)row * 768 + col] = xv;
    Xb[(size_t)row * 768 + col] = (bf16)xv;
    sn += xv * xv;
  }
#pragma unroll
  for (int off = 32; off; off >>= 1) sn += __shfl_xor(sn, off, 64);
  if (lane == 0) xn2[row] = sn;
}

// ---------------- gather C0 = X[idx] (f32 + bf16), zero control ----------------
__global__ __launch_bounds__(256) void gather_init(
    const float* __restrict__ X, const int* __restrict__ idx,
    float* __restrict__ Cbuf, bf16* __restrict__ Cbh, float* __restrict__ cn,
    float* __restrict__ asum, float* __restrict__ diff,
    int* flag, int* rp, int* dctr)
{
  const int k = blockIdx.x;
  const int src = idx[k];
  __shared__ float red[4];
  float s = 0.f;
#pragma unroll
  for (int u = 0; u < 3; ++u) {
    int d = u * 256 + threadIdx.x;
    float v = X[(size_t)src * 768 + d];
    Cbuf[(size_t)k * 768 + d] = v;
    Cbh[(size_t)k * 768 + d] = (bf16)v;
    s += v * v;
  }
#pragma unroll
  for (int off = 32; off; off >>= 1) s += __shfl_xor(s, off, 64);
  if ((threadIdx.x & 63) == 0) red[threadIdx.x >> 6] = s;
  __syncthreads();
  if (threadIdx.x == 0) cn[k] = red[0] + red[1] + red[2] + red[3];
  if (k == 0) {
    if (threadIdx.x < 64) {
      asum[threadIdx.x] = 0.f;
      asum[64 + threadIdx.x] = 0.f;
      cn[64 + threadIdx.x] = 0.f;
    }
    if (threadIdx.x == 0) {
      diff[0] = 0.f; diff[1] = 0.f; *flag = 0; *rp = 0; *dctr = 0;
    }
  }
}

// ---------------- DKM step part 1: a = softmax(-2*dist), a_sum ----------------
__global__ __launch_bounds__(256) void dkm_assign(
    const bf16* __restrict__ Cbhall, const float* __restrict__ cnall, int t,
    const bf16* __restrict__ Xb, const float* __restrict__ xn2,
    float* __restrict__ a_out, bf16* __restrict__ aT,
    float* __restrict__ asumall, const int* flag)
{
  if (*(volatile const int*)flag) return;
  const bf16* C  = Cbhall + (size_t)(t & 1) * 49152;
  const float* cn = cnall + (t & 1) * 64;
  float* asum = asumall + (t & 1) * 64;
  __shared__ float Gs[16][64];
  __shared__ float asl[64];
  const int w = threadIdx.x >> 6, lane = threadIdx.x & 63;
  const int q2 = lane >> 4, c = lane & 15;
  const int rbase = blockIdx.x * 16;
  f32x4 acc = {};
  const bf16* Ar = Xb + (size_t)(rbase + c) * 768 + q2 * 8;
  const bf16* Cr = C + (size_t)(w * 16 + c) * 768 + q2 * 8;
  for (int ks = 0; ks < 24; ++ks) {
    bf16x8 a = *(const bf16x8*)(Ar + ks * 32);
    bf16x8 b = *(const bf16x8*)(Cr + ks * 32);
    acc = mfma16(a, b, acc);
  }
  if (threadIdx.x < 64) asl[threadIdx.x] = 0.f;
#pragma unroll
  for (int j = 0; j < 4; ++j) Gs[q2 * 4 + j][w * 16 + c] = acc[j];
  __syncthreads();
  const int row = threadIdx.x >> 4, ci = threadIdx.x & 15;
  const float xn = xn2[rbase + row];
  float lg[4];
#pragma unroll
  for (int u = 0; u < 4; ++u) {
    int col = ci + u * 16;
    float d2 = xn + cn[col] - 2.f * Gs[row][col];
    lg[u] = -2.f * sqrtf(fmaxf(d2, 0.f));   // -d / TEMP, TEMP=0.5
  }
  float mx = fmaxf(fmaxf(lg[0], lg[1]), fmaxf(lg[2], lg[3]));
#pragma unroll
  for (int off = 8; off; off >>= 1) mx = fmaxf(mx, __shfl_xor(mx, off, 16));
  float sum = 0.f;
#pragma unroll
  for (int u = 0; u < 4; ++u) { float e = exp2f((lg[u] - mx) * LOG2E); lg[u] = e; sum += e; }
#pragma unroll
  for (int off = 8; off; off >>= 1) sum += __shfl_xor(sum, off, 16);
#pragma unroll
  for (int u = 0; u < 4; ++u) {
    int col = ci + u * 16;
    float av = lg[u] / sum;
    a_out[(size_t)(rbase + row) * 64 + col] = av;
    aT[(size_t)col * 4096 + rbase + row] = (bf16)av;
    atomicAdd(&asl[col], av);
  }
  __syncthreads();
  if (threadIdx.x < 64) atomicAdd(&asum[threadIdx.x], asl[threadIdx.x]);
}

// ---------------- DKM step part 2: C_new = a^T @ X / a_sum, diff, flag ----------------
__global__ __launch_bounds__(256) void dkm_update(
    float* __restrict__ Call, bf16* __restrict__ Cbhall,
    float* __restrict__ cnall, int t,
    const bf16* __restrict__ aT, const bf16* __restrict__ Xt,
    float* __restrict__ asumall, float* __restrict__ diffall,
    int* flag, int* rp, int* dctr)
{
  if (*(volatile int*)flag) return;
  const int w = threadIdx.x >> 6, lane = threadIdx.x & 63;
  const int q2 = lane >> 4, c = lane & 15;
  const int tr = blockIdx.x / 48, tc = blockIdx.x % 48;
  f32x4 acc = {};
  const bf16* Ar = aT + (size_t)(tr * 16 + c) * 4096 + q2 * 8;
  const bf16* Br = Xt + (size_t)(tc * 16 + c) * 4096 + q2 * 8;
  for (int i = 0; i < 32; ++i) {
    int kb = (w + i * 4) * 32;
    acc = mfma16(*(const bf16x8*)(Ar + kb), *(const bf16x8*)(Br + kb), acc);
  }
  __shared__ float red[4][16][16];
  __shared__ float cnl[16];
  __shared__ float dred[4];
#pragma unroll
  for (int j = 0; j < 4; ++j) red[w][q2 * 4 + j][c] = acc[j];
  if (threadIdx.x < 16) cnl[threadIdx.x] = 0.f;
  __syncthreads();
  const int r = threadIdx.x >> 4, cl = threadIdx.x & 15;
  float s = red[0][r][cl] + red[1][r][cl] + red[2][r][cl] + red[3][r][cl];
  const int cluster = tr * 16 + r, dcol = tc * 16 + cl;
  float denom = asumall[(t & 1) * 64 + cluster] + 1e-6f;
  float cnew = s / denom;
  size_t cidx = (size_t)cluster * 768 + dcol;
  float cold = Call[(size_t)(t & 1) * 49152 + cidx];
  Call[(size_t)((t + 1) & 1) * 49152 + cidx] = cnew;
  Cbhall[(size_t)((t + 1) & 1) * 49152 + cidx] = (bf16)cnew;
  atomicAdd(&cnl[r], cnew * cnew);
  float dv = fabsf(cnew - cold);
#pragma unroll
  for (int off = 32; off; off >>= 1) dv += __shfl_xor(dv, off, 64);
  if (lane == 0) dred[w] = dv;
  __syncthreads();
  if (threadIdx.x < 16)
    atomicAdd(&cnall[((t + 1) & 1) * 64 + tr * 16 + threadIdx.x], cnl[threadIdx.x]);
  if (threadIdx.x == 0) {
    atomicAdd(&diffall[t & 1], dred[0] + dred[1] + dred[2] + dred[3]);
    __threadfence();
    int old = atomicAdd(dctr, 1);
    if (old == 191) {   // last block of this dispatch
      float dtot = atomicAdd(&diffall[t & 1], 0.f);
      if (dtot <= 1e-4f) { *flag = 1; *rp = (t & 1); }
      diffall[(t + 1) & 1] = 0.f;
      for (int i = 0; i < 64; ++i) {
        asumall[((t + 1) & 1) * 64 + i] = 0.f;
        cnall[(t & 1) * 64 + i] = 0.f;
      }
      *dctr = 0;
    }
  }
}

// ---------------- final: copy converged C (parity rp) to d_out ----------------
__global__ __launch_bounds__(256) void copy_c(const float* __restrict__ Call,
                                              const int* __restrict__ rp,
                                              float* __restrict__ out)
{
  const float* src = Call + (size_t)(*rp) * 49152;
  int i = blockIdx.x * 256 + threadIdx.x;
#pragma unroll
  for (int u = 0; u < 4; ++u) out[i + u * 12288] = src[i + u * 12288];
}

extern "C" void kernel_launch(void* const* d_in, const int* in_sizes, int n_in,
                              void* d_out, int out_size, void* d_ws, size_t ws_size,
                              hipStream_t stream) {
  const float* x0   = (const float*)d_in[0];
  const float* fc1w = (const float*)d_in[1];
  const float* fc1b = (const float*)d_in[2];
  const float* fc2w = (const float*)d_in[3];
  const float* fc2b = (const float*)d_in[4];
  const float* ipw  = (const float*)d_in[5];
  const float* ipb  = (const float*)d_in[6];
  const float* outw = (const float*)d_in[7];
  const float* outbias = (const float*)d_in[8];
  const float* lng  = (const float*)d_in[9];
  const float* lnb  = (const float*)d_in[10];
  const int*   idx  = (const int*)d_in[11];

  char* p = (char*)d_ws;
  auto take = [&](size_t n) { char* r = p; p += (n + 255) & ~(size_t)255; return r; };
  bf16* X0B   = (bf16*)take((size_t)4096 * 768 * 2);
  bf16* W1B   = (bf16*)take((size_t)768 * 768 * 2);
  bf16* FC2WB = (bf16*)take((size_t)768 * 768 * 2);
  bf16* IPWB  = (bf16*)take((size_t)2304 * 768 * 2);
  bf16* OUTWB = (bf16*)take((size_t)768 * 768 * 2);
  bf16* HB    = (bf16*)take((size_t)4096 * 768 * 2);
  bf16* QKVB  = (bf16*)take((size_t)4096 * 2304 * 2);
  bf16* VT    = (bf16*)take((size_t)768 * 4096 * 2);
  bf16* OB    = (bf16*)take((size_t)4096 * 768 * 2);
  bf16* O2B   = (bf16*)take((size_t)4096 * 768 * 2);
  float* YF   = (float*)take((size_t)4096 * 768 * 4);
  float* XF   = (float*)take((size_t)4096 * 768 * 4);
  bf16* XBB   = (bf16*)take((size_t)4096 * 768 * 2);
  bf16* XTB   = (bf16*)take((size_t)768 * 4096 * 2);
  float* XN2  = (float*)take((size_t)4096 * 4);
  float* CB   = (float*)take((size_t)2 * 49152 * 4);
  bf16* CBH   = (bf16*)take((size_t)2 * 49152 * 2);
  bf16* ATB   = (bf16*)take((size_t)64 * 4096 * 2);
  float* ASUM = (float*)take(2 * 64 * 4);
  float* CN   = (float*)take(2 * 64 * 4);
  float* CTRL = (float*)take(256);
  float* DIFF = CTRL;               // [2] floats
  int* FLAG = (int*)(CTRL + 2);
  int* RP   = (int*)(CTRL + 3);
  int* DCTR = (int*)(CTRL + 4);

  float* aout = (float*)d_out + 49152;

  cvt_all<<<6528, 256, 0, stream>>>(x0, fc1w, fc2w, ipw, outw, X0B, W1B, FC2WB, IPWB, OUTWB);
  gemm_bt<1, 0><<<dim3(64, 12), 256, 0, stream>>>(X0B, W1B, fc1b, HB, nullptr, 768);
  gemm_bt<0, 0><<<dim3(64, 36), 256, 0, stream>>>(HB, IPWB, ipb, QKVB, nullptr, 2304);
  transpose_bf16<<<dim3(64, 12), 256, 0, stream>>>(QKVB, VT, 2304, 1536);
  attn_kernel<<<768, 256, 0, stream>>>(QKVB, VT, OB);
  gemm_bt<0, 0><<<dim3(64, 12), 256, 0, stream>>>(OB, OUTWB, outbias, O2B, nullptr, 768);
  gemm_bt<1, 1><<<dim3(64, 12), 256, 0, stream>>>(O2B, FC2WB, fc2b, nullptr, YF, 768);
  ln_kernel<<<1024, 256, 0, stream>>>(x0, YF, lng, lnb, XF, XBB, XN2);
  transpose_bf16<<<dim3(64, 12), 256, 0, stream>>>(XBB, XTB, 768, 0);
  gather_init<<<64, 256, 0, stream>>>(XF, idx, CB, CBH, CN, ASUM, DIFF, FLAG, RP, DCTR);
  for (int t = 0; t <= 100; ++t) {
    dkm_assign<<<256, 256, 0, stream>>>(CBH, CN, t, XBB, XN2, aout, ATB, ASUM, FLAG);
    dkm_update<<<192, 256, 0, stream>>>(CB, CBH, CN, t, ATB, XTB, ASUM, DIFF, FLAG, RP, DCTR);
  }
  copy_c<<<48, 256, 0, stream>>>(CB, RP, (float*)d_out);
}